// Round 7
// baseline (289.524 us; speedup 1.0000x reference)
//
#include <hip/hip_runtime.h>
#include <hip/hip_bf16.h>
#include <math.h>

#define S 4096
#define CIN 256
#define C3 768
#define NH 8
#define HD 32
#define KSPLIT 2

static constexpr float EPS = 1e-4f;

typedef __attribute__((ext_vector_type(8))) __bf16 bf16x8;
typedef __attribute__((ext_vector_type(4))) float f32x4;
typedef __attribute__((ext_vector_type(8))) unsigned short u16x8;

static inline __device__ ushort f2bf(float f) {  // RN-even
  unsigned u = __float_as_uint(f);
  return (ushort)((u + 0x7fffu + ((u >> 16) & 1u)) >> 16);
}
static inline __device__ float bf2f(ushort u) {
  return __uint_as_float(((unsigned)u) << 16);
}
// pack two positive floats to bf16x2 (round-by-add, 3 VALU ops total)
static inline __device__ unsigned pack2bf(float lo, float hi) {
  unsigned a = __float_as_uint(lo) + 0x8000u;
  unsigned b = __float_as_uint(hi) + 0x8000u;
  return __builtin_amdgcn_perm(b, a, 0x07060302);
}

// ---------------- weight norm (both weights, one launch) ---------------------
__global__ __launch_bounds__(256) void wnorm_kernel(const float* __restrict__ w_qkv,
                                                    const float* __restrict__ w_out,
                                                    ushort* __restrict__ wqb,
                                                    ushort* __restrict__ wob) {
  const int row = blockIdx.x * 4 + (threadIdx.x >> 6);
  const int lane = threadIdx.x & 63;
  const bool is_q = row < C3;
  const float* wr = (is_q ? w_qkv + (size_t)row * CIN : w_out + (size_t)(row - C3) * CIN);
  float v0 = wr[lane], v1 = wr[lane + 64], v2 = wr[lane + 128], v3 = wr[lane + 192];
  float ss = v0 * v0 + v1 * v1 + v2 * v2 + v3 * v3;
  #pragma unroll
  for (int off = 32; off > 0; off >>= 1) ss += __shfl_down(ss, off, 64);
  ss = __shfl(ss, 0, 64);
  const float scale = 1.0f / (sqrtf(ss) + 16.0f * EPS);
  ushort* whr = (is_q ? wqb + (size_t)row * CIN : wob + (size_t)(row - C3) * CIN);
  whr[lane] = f2bf(v0 * scale);
  whr[lane + 64] = f2bf(v1 * scale);
  whr[lane + 128] = f2bf(v2 * scale);
  whr[lane + 192] = f2bf(v3 * scale);
}

// ---------------- X [b][c][s] fp32 -> Xt [b][s][c] bf16 ----------------------
__global__ __launch_bounds__(256) void xt_kernel(const float* __restrict__ X,
                                                 ushort* __restrict__ Xt) {
  const int b = blockIdx.z;
  const int s0 = blockIdx.x * 64, c0 = blockIdx.y * 64;
  __shared__ ushort T[64][72];
  const int tc = threadIdx.x >> 4;
  const int ts = threadIdx.x & 15;
  #pragma unroll
  for (int i = 0; i < 4; i++) {
    const float4 v = *(const float4*)&X[((size_t)(b * CIN + c0 + tc + 16 * i)) * S + s0 + ts * 4];
    ushort4 u;
    u.x = f2bf(v.x); u.y = f2bf(v.y); u.z = f2bf(v.z); u.w = f2bf(v.w);
    *(ushort4*)&T[tc + 16 * i][ts * 4] = u;
  }
  __syncthreads();
  #pragma unroll
  for (int i = 0; i < 4; i++) {
    const int sr = tc + 16 * i;
    ushort4 u;
    u.x = T[ts * 4 + 0][sr];
    u.y = T[ts * 4 + 1][sr];
    u.z = T[ts * 4 + 2][sr];
    u.w = T[ts * 4 + 3][sr];
    *(ushort4*)&Xt[((size_t)b * S + s0 + sr) * CIN + c0 + ts * 4] = u;
  }
}

// ---------------- MFMA 1x1 conv: OUT[m][n] = sum_k W[m][k] B[n][k] -----------
template <int MOUT, int MODE>
__global__ __launch_bounds__(256) void conv_mfma_kernel(const ushort* __restrict__ W,
                                                        const ushort* __restrict__ Bm,
                                                        void* __restrict__ OUTv,
                                                        const float* __restrict__ RES) {
  const int b = blockIdx.z;
  const int wid = threadIdx.x >> 6, lane = threadIdx.x & 63;
  const int col = lane & 15, quad = lane >> 4;
  const int m0 = blockIdx.y * 64 + (wid >> 1) * 32;
  const int n0 = blockIdx.x * 128 + (wid & 1) * 64;
  const ushort* Bb = Bm + (size_t)b * S * CIN;
  f32x4 acc[2][4] = {};
  #pragma unroll
  for (int k0 = 0; k0 < CIN; k0 += 32) {
    bf16x8 af[2], bf[4];
    #pragma unroll
    for (int mi = 0; mi < 2; mi++)
      af[mi] = *(const bf16x8*)&W[(size_t)(m0 + mi * 16 + col) * CIN + k0 + quad * 8];
    #pragma unroll
    for (int ni = 0; ni < 4; ni++)
      bf[ni] = *(const bf16x8*)&Bb[(size_t)(n0 + ni * 16 + col) * CIN + k0 + quad * 8];
    #pragma unroll
    for (int mi = 0; mi < 2; mi++)
      #pragma unroll
      for (int ni = 0; ni < 4; ni++)
        acc[mi][ni] = __builtin_amdgcn_mfma_f32_16x16x32_bf16(af[mi], bf[ni], acc[mi][ni], 0, 0, 0);
  }
  if (MODE == 0) {
    ushort* O = (ushort*)OUTv;
    #pragma unroll
    for (int mi = 0; mi < 2; mi++)
      #pragma unroll
      for (int ni = 0; ni < 4; ni++) {
        ushort4 u;
        u.x = f2bf(acc[mi][ni][0]);
        u.y = f2bf(acc[mi][ni][1]);
        u.z = f2bf(acc[mi][ni][2]);
        u.w = f2bf(acc[mi][ni][3]);
        *(ushort4*)&O[((size_t)b * S + n0 + ni * 16 + col) * MOUT + m0 + mi * 16 + quad * 4] = u;
      }
  } else {
    float* O = (float*)OUTv;
    const float tc = 0.3f, om = 0.7f, inv = 1.3130643285972254f;
    #pragma unroll
    for (int mi = 0; mi < 2; mi++)
      #pragma unroll
      for (int ni = 0; ni < 4; ni++)
        #pragma unroll
        for (int r = 0; r < 4; r++) {
          const size_t idx = ((size_t)(b * MOUT + m0 + mi * 16 + quad * 4 + r)) * S + n0 + ni * 16 + col;
          O[idx] = (om * RES[idx] + tc * acc[mi][ni][r]) * inv;
        }
  }
}

// ---------------- pixel norm + layout fan-out --------------------------------
// Q additionally pre-scaled by log2(e)/sqrt(32) so attention skips the mul.
__global__ __launch_bounds__(256) void pixnorm_kernel(const ushort* __restrict__ qkvT,
                                                      ushort* __restrict__ Qn,
                                                      ushort* __restrict__ Kn,
                                                      ushort* __restrict__ Vt) {
  const int b = blockIdx.z, g = blockIdx.y;
  const int s = blockIdx.x * 256 + threadIdx.x;
  const ushort* src = qkvT + ((size_t)b * S + s) * C3 + g * HD;
  float v[HD];
  float ss = 0.f;
  #pragma unroll
  for (int i = 0; i < 8; i++) {
    ushort4 u = *(const ushort4*)&src[i * 4];
    float f0 = bf2f(u.x), f1 = bf2f(u.y), f2 = bf2f(u.z), f3 = bf2f(u.w);
    v[i * 4 + 0] = f0; v[i * 4 + 1] = f1; v[i * 4 + 2] = f2; v[i * 4 + 3] = f3;
    ss += f0 * f0 + f1 * f1 + f2 * f2 + f3 * f3;
  }
  float r = rsqrtf(ss * (1.0f / HD) + EPS);
  if (g < 16) {
    if (g < 8) r *= 0.2550348190698169f;  // log2(e)/sqrt(32) folded into Q
    ushort* dst = (g < 8 ? Qn : Kn) + ((size_t)(b * NH + (g & 7)) * S + s) * HD;
    #pragma unroll
    for (int i = 0; i < 8; i++) {
      ushort4 u;
      u.x = f2bf(v[i * 4 + 0] * r);
      u.y = f2bf(v[i * 4 + 1] * r);
      u.z = f2bf(v[i * 4 + 2] * r);
      u.w = f2bf(v[i * 4 + 3] * r);
      *(ushort4*)&dst[i * 4] = u;
    }
  } else {
    ushort* dst = Vt + ((size_t)(b * NH + (g - 16)) * HD) * S + s;
    #pragma unroll
    for (int d = 0; d < HD; d++) dst[(size_t)d * S] = f2bf(v[d] * r);
  }
}

// ---------------- MFMA attention, 16 q/wave, K-split x2 ----------------------
// Per wave: 16 queries x 2048 keys. The 16x16x32 MFMA B-operand is exactly 16
// columns, so a 16-query wave wastes nothing; waves double vs 32q (8192 total)
// -> 8 blocks/CU, 32 waves/CU for 2x latency hiding at identical per-element
// cost and identical HBM traffic (K/V still L2-shared across q-blocks).
// S^T = K.Q^T (Q pre-scaled -> exp2 direct); P bf16 via v_perm; l via ones-A
// MFMA; PV as out^T = V^T.P^T through per-wave LDS (no barriers).
// grid (S/64, NH*KSPLIT, B), block 256 (4 waves), single-buffer P (9.2 KB).
__global__ __launch_bounds__(256, 8) void attn_kernel(const ushort* __restrict__ Qn,
                                                      const ushort* __restrict__ Kn,
                                                      const ushort* __restrict__ Vt,
                                                      float* __restrict__ accP,
                                                      float* __restrict__ lP) {
  const int b = blockIdx.z;
  const int h = blockIdx.y & 7, kp = blockIdx.y >> 3;
  const int wid = threadIdx.x >> 6, lane = threadIdx.x & 63;
  const int col = lane & 15, quad = lane >> 4;
  const int q0 = blockIdx.x * 64 + wid * 16;

  __shared__ ushort P_lds[4][16][72];
  ushort(*__restrict__ P)[72] = P_lds[wid];

  const ushort* Qh = Qn + (size_t)(b * NH + h) * S * HD;
  const ushort* Kh = Kn + (size_t)(b * NH + h) * S * HD;
  const ushort* Vh = Vt + (size_t)(b * NH + h) * HD * S;

  const bf16x8 qf = *(const bf16x8*)&Qh[(size_t)(q0 + col) * HD + quad * 8];

  const u16x8 ou = {0x3F80, 0x3F80, 0x3F80, 0x3F80, 0x3F80, 0x3F80, 0x3F80, 0x3F80};
  const bf16x8 ones = __builtin_bit_cast(bf16x8, ou);
  const f32x4 z = {0.f, 0.f, 0.f, 0.f};

  f32x4 acc[2] = {};
  f32x4 accl = {};

  const int kt0 = kp * (S / KSPLIT), kt1 = kt0 + S / KSPLIT;
  bf16x8 kf[4];
  #pragma unroll
  for (int mt = 0; mt < 4; mt++)
    kf[mt] = *(const bf16x8*)&Kh[(size_t)(kt0 + mt * 16 + col) * HD + quad * 8];

  for (int kt = kt0; kt < kt1; kt += 64) {
    // S-phase: 64 keys x 16 q; prefetch next tile's K frags (reads past the
    // partition end stay inside the workspace -> harmless, never used)
    #pragma unroll
    for (int mt = 0; mt < 4; mt++) {
      f32x4 s0 = __builtin_amdgcn_mfma_f32_16x16x32_bf16(kf[mt], qf, z, 0, 0, 0);
      kf[mt] = *(const bf16x8*)&Kh[(size_t)(kt + 64 + mt * 16 + col) * HD + quad * 8];
      uint2 w;
      w.x = pack2bf(__builtin_amdgcn_exp2f(s0[0]), __builtin_amdgcn_exp2f(s0[1]));
      w.y = pack2bf(__builtin_amdgcn_exp2f(s0[2]), __builtin_amdgcn_exp2f(s0[3]));
      *(uint2*)&P[col][mt * 16 + quad * 4] = w;
    }

    // PV: out^T += V^T . P^T (wave-private LDS, lgkmcnt orders write->read)
    #pragma unroll
    for (int kc = 0; kc < 2; kc++) {
      bf16x8 pf = *(const bf16x8*)&P[col][kc * 32 + quad * 8];
      accl = __builtin_amdgcn_mfma_f32_16x16x32_bf16(ones, pf, accl, 0, 0, 0);
      #pragma unroll
      for (int dt = 0; dt < 2; dt++) {
        bf16x8 vf = *(const bf16x8*)&Vh[(size_t)(dt * 16 + col) * S + kt + kc * 32 + quad * 8];
        acc[dt] = __builtin_amdgcn_mfma_f32_16x16x32_bf16(vf, pf, acc[dt], 0, 0, 0);
      }
    }
  }

  float* ap = accP + ((size_t)((kp * 2 + b) * NH + h)) * S * HD;
  #pragma unroll
  for (int dt = 0; dt < 2; dt++) {
    float4 u;
    u.x = acc[dt][0];
    u.y = acc[dt][1];
    u.z = acc[dt][2];
    u.w = acc[dt][3];
    *(float4*)&ap[(size_t)(q0 + col) * HD + dt * 16 + quad * 4] = u;
  }
  if (quad == 0)
    lP[((size_t)((kp * 2 + b) * NH + h)) * S + q0 + col] = accl[0];
}

// ---------------- combine K-split partials -> Yt [b][s][256] bf16 ------------
// one thread per (b,h,q,dg): 2*8*4096*8 = 524288 threads = 2048 blocks.
__global__ __launch_bounds__(256) void combine_kernel(const float* __restrict__ accP,
                                                      const float* __restrict__ lP,
                                                      ushort* __restrict__ Yt) {
  const int tid = blockIdx.x * 256 + threadIdx.x;
  const int dg = tid & 7;
  const int q = (tid >> 3) & (S - 1);
  const int h = (tid >> 15) & 7;
  const int b = tid >> 18;
  const size_t i0 = ((size_t)(b * NH + h)) * S + q;
  const size_t part = (size_t)2 * NH * S;
  float sx = 0.f, sy = 0.f, sz = 0.f, sw = 0.f, L = 0.f;
  #pragma unroll
  for (int p = 0; p < KSPLIT; p++) {
    const float4 a = *(const float4*)&accP[(size_t)p * part * HD + i0 * HD + dg * 4];
    sx += a.x; sy += a.y; sz += a.z; sw += a.w;
    L += lP[(size_t)p * part + i0];
  }
  const float rl = 1.0f / L;
  ushort4 o;
  o.x = f2bf(sx * rl);
  o.y = f2bf(sy * rl);
  o.z = f2bf(sz * rl);
  o.w = f2bf(sw * rl);
  *(ushort4*)&Yt[((size_t)b * S + q) * CIN + h * HD + dg * 4] = o;
}

// ---------------- launch ----------------
extern "C" void kernel_launch(void* const* d_in, const int* in_sizes, int n_in,
                              void* d_out, int out_size, void* d_ws, size_t ws_size,
                              hipStream_t stream) {
  const float* x = (const float*)d_in[0];
  const float* w_qkv = (const float*)d_in[1];
  const float* w_out = (const float*)d_in[2];
  float* out = (float*)d_out;

  ushort* p = (ushort*)d_ws;
  ushort* wqb = p; p += (size_t)C3 * CIN;
  ushort* wob = p; p += (size_t)CIN * CIN;
  ushort* Qn = p; p += (size_t)2 * NH * S * HD;
  ushort* Kn = p; p += (size_t)2 * NH * S * HD;
  ushort* Vt = p; p += (size_t)2 * NH * S * HD;
  ushort* Yt = p; p += (size_t)2 * S * CIN;
  // Region R: Xt (4 MB) + qkvT (12.6 MB) die after pixnorm; accP fp32
  // (KSPLIT*2*8*4096*32 floats = 16.78 MB) aliases the same region exactly.
  ushort* R = p; p += (size_t)2 * S * CIN + (size_t)2 * S * C3;
  ushort* Xt = R;
  ushort* qkvT = R + (size_t)2 * S * CIN;
  float* accP = (float*)R;
  float* lP = (float*)p;  // KSPLIT*2*8*4096 floats = 0.5 MB

  wnorm_kernel<<<(C3 + CIN) / 4, 256, 0, stream>>>(w_qkv, w_out, wqb, wob);
  xt_kernel<<<dim3(S / 64, CIN / 64, 2), 256, 0, stream>>>(x, Xt);
  conv_mfma_kernel<C3, 0><<<dim3(S / 128, C3 / 64, 2), 256, 0, stream>>>(wqb, Xt, qkvT, nullptr);
  pixnorm_kernel<<<dim3(S / 256, 24, 2), 256, 0, stream>>>(qkvT, Qn, Kn, Vt);
  attn_kernel<<<dim3(S / 64, NH * KSPLIT, 2), 256, 0, stream>>>(Qn, Kn, Vt, accP, lP);
  combine_kernel<<<2048, 256, 0, stream>>>(accP, lP, Yt);
  conv_mfma_kernel<CIN, 1><<<dim3(S / 128, CIN / 64, 2), 256, 0, stream>>>(wob, Yt, out, x);
}

// Round 8
// 212.869 us; speedup vs baseline: 1.3601x; 1.3601x over previous
//
#include <hip/hip_runtime.h>
#include <hip/hip_bf16.h>
#include <math.h>

#define S 4096
#define CIN 256
#define C3 768
#define NH 8
#define HD 32
#define KSPLIT 2
#define PW 80  // P row stride in ushorts: 160 B = 40 words -> 4-way max conflict, 16B-aligned

static constexpr float EPS = 1e-4f;

typedef __attribute__((ext_vector_type(8))) __bf16 bf16x8;
typedef __attribute__((ext_vector_type(4))) float f32x4;
typedef __attribute__((ext_vector_type(8))) unsigned short u16x8;

static inline __device__ ushort f2bf(float f) {  // RN-even
  unsigned u = __float_as_uint(f);
  return (ushort)((u + 0x7fffu + ((u >> 16) & 1u)) >> 16);
}
static inline __device__ float bf2f(ushort u) {
  return __uint_as_float(((unsigned)u) << 16);
}
// pack two floats to bf16x2 (round-by-add; works for signed values)
static inline __device__ unsigned pack2bf(float lo, float hi) {
  unsigned a = __float_as_uint(lo) + 0x8000u;
  unsigned b = __float_as_uint(hi) + 0x8000u;
  return __builtin_amdgcn_perm(b, a, 0x07060302);
}

// ---------------- weight norm (both weights, one launch) ---------------------
__global__ __launch_bounds__(256) void wnorm_kernel(const float* __restrict__ w_qkv,
                                                    const float* __restrict__ w_out,
                                                    ushort* __restrict__ wqb,
                                                    ushort* __restrict__ wob) {
  const int row = blockIdx.x * 4 + (threadIdx.x >> 6);
  const int lane = threadIdx.x & 63;
  const bool is_q = row < C3;
  const float* wr = (is_q ? w_qkv + (size_t)row * CIN : w_out + (size_t)(row - C3) * CIN);
  float v0 = wr[lane], v1 = wr[lane + 64], v2 = wr[lane + 128], v3 = wr[lane + 192];
  float ss = v0 * v0 + v1 * v1 + v2 * v2 + v3 * v3;
  #pragma unroll
  for (int off = 32; off > 0; off >>= 1) ss += __shfl_down(ss, off, 64);
  ss = __shfl(ss, 0, 64);
  const float scale = 1.0f / (sqrtf(ss) + 16.0f * EPS);
  ushort* whr = (is_q ? wqb + (size_t)row * CIN : wob + (size_t)(row - C3) * CIN);
  whr[lane] = f2bf(v0 * scale);
  whr[lane + 64] = f2bf(v1 * scale);
  whr[lane + 128] = f2bf(v2 * scale);
  whr[lane + 192] = f2bf(v3 * scale);
}

// ---------------- X [b][c][s] fp32 -> Xt [b][s][c] bf16 ----------------------
__global__ __launch_bounds__(256) void xt_kernel(const float* __restrict__ X,
                                                 ushort* __restrict__ Xt) {
  const int b = blockIdx.z;
  const int s0 = blockIdx.x * 64, c0 = blockIdx.y * 64;
  __shared__ ushort T[64][72];
  const int tc = threadIdx.x >> 4;
  const int ts = threadIdx.x & 15;
  #pragma unroll
  for (int i = 0; i < 4; i++) {
    const float4 v = *(const float4*)&X[((size_t)(b * CIN + c0 + tc + 16 * i)) * S + s0 + ts * 4];
    ushort4 u;
    u.x = f2bf(v.x); u.y = f2bf(v.y); u.z = f2bf(v.z); u.w = f2bf(v.w);
    *(ushort4*)&T[tc + 16 * i][ts * 4] = u;
  }
  __syncthreads();
  #pragma unroll
  for (int i = 0; i < 4; i++) {
    const int sr = tc + 16 * i;
    ushort4 u;
    u.x = T[ts * 4 + 0][sr];
    u.y = T[ts * 4 + 1][sr];
    u.z = T[ts * 4 + 2][sr];
    u.w = T[ts * 4 + 3][sr];
    *(ushort4*)&Xt[((size_t)b * S + s0 + sr) * CIN + c0 + ts * 4] = u;
  }
}

// ---------------- conv1: qkvT[b][s][768] bf16 = Wq . Xt ----------------------
__global__ __launch_bounds__(256) void conv1_kernel(const ushort* __restrict__ W,
                                                    const ushort* __restrict__ Bm,
                                                    ushort* __restrict__ O) {
  const int b = blockIdx.z;
  const int wid = threadIdx.x >> 6, lane = threadIdx.x & 63;
  const int col = lane & 15, quad = lane >> 4;
  const int m0 = blockIdx.y * 64 + (wid >> 1) * 32;
  const int n0 = blockIdx.x * 128 + (wid & 1) * 64;
  const ushort* Bb = Bm + (size_t)b * S * CIN;
  f32x4 acc[2][4] = {};
  #pragma unroll
  for (int k0 = 0; k0 < CIN; k0 += 32) {
    bf16x8 af[2], bf[4];
    #pragma unroll
    for (int mi = 0; mi < 2; mi++)
      af[mi] = *(const bf16x8*)&W[(size_t)(m0 + mi * 16 + col) * CIN + k0 + quad * 8];
    #pragma unroll
    for (int ni = 0; ni < 4; ni++)
      bf[ni] = *(const bf16x8*)&Bb[(size_t)(n0 + ni * 16 + col) * CIN + k0 + quad * 8];
    #pragma unroll
    for (int mi = 0; mi < 2; mi++)
      #pragma unroll
      for (int ni = 0; ni < 4; ni++)
        acc[mi][ni] = __builtin_amdgcn_mfma_f32_16x16x32_bf16(af[mi], bf[ni], acc[mi][ni], 0, 0, 0);
  }
  #pragma unroll
  for (int mi = 0; mi < 2; mi++)
    #pragma unroll
    for (int ni = 0; ni < 4; ni++) {
      ushort4 u;
      u.x = f2bf(acc[mi][ni][0]);
      u.y = f2bf(acc[mi][ni][1]);
      u.z = f2bf(acc[mi][ni][2]);
      u.w = f2bf(acc[mi][ni][3]);
      *(ushort4*)&O[((size_t)b * S + n0 + ni * 16 + col) * C3 + m0 + mi * 16 + quad * 4] = u;
    }
}

// ---------------- pixel norm + layout fan-out --------------------------------
// Q additionally pre-scaled by log2(e)/sqrt(32) so attention skips the mul.
__global__ __launch_bounds__(256) void pixnorm_kernel(const ushort* __restrict__ qkvT,
                                                      ushort* __restrict__ Qn,
                                                      ushort* __restrict__ Kn,
                                                      ushort* __restrict__ Vt) {
  const int b = blockIdx.z, g = blockIdx.y;
  const int s = blockIdx.x * 256 + threadIdx.x;
  const ushort* src = qkvT + ((size_t)b * S + s) * C3 + g * HD;
  float v[HD];
  float ss = 0.f;
  #pragma unroll
  for (int i = 0; i < 8; i++) {
    ushort4 u = *(const ushort4*)&src[i * 4];
    float f0 = bf2f(u.x), f1 = bf2f(u.y), f2 = bf2f(u.z), f3 = bf2f(u.w);
    v[i * 4 + 0] = f0; v[i * 4 + 1] = f1; v[i * 4 + 2] = f2; v[i * 4 + 3] = f3;
    ss += f0 * f0 + f1 * f1 + f2 * f2 + f3 * f3;
  }
  float r = rsqrtf(ss * (1.0f / HD) + EPS);
  if (g < 16) {
    if (g < 8) r *= 0.2550348190698169f;  // log2(e)/sqrt(32) folded into Q
    ushort* dst = (g < 8 ? Qn : Kn) + ((size_t)(b * NH + (g & 7)) * S + s) * HD;
    #pragma unroll
    for (int i = 0; i < 8; i++) {
      ushort4 u;
      u.x = f2bf(v[i * 4 + 0] * r);
      u.y = f2bf(v[i * 4 + 1] * r);
      u.z = f2bf(v[i * 4 + 2] * r);
      u.w = f2bf(v[i * 4 + 3] * r);
      *(ushort4*)&dst[i * 4] = u;
    }
  } else {
    ushort* dst = Vt + ((size_t)(b * NH + (g - 16)) * HD) * S + s;
    #pragma unroll
    for (int d = 0; d < HD; d++) dst[(size_t)d * S] = f2bf(v[d] * r);
  }
}

// ---------------- MFMA attention, 32 q/wave, K-split x2 ----------------------
// R4 structure (proven 101 us) with the P LDS stride changed 72 -> 80 ushorts:
// bank = (8*(col mod 4) + 4*quad) mod 32 -> max 4-way conflicts (was 8-way).
// S^T = K.Q^T (Q pre-scaled -> exp2 direct); P bf16 via v_perm; l via ones-A
// MFMA; PV as out^T = V^T.P^T through per-wave LDS (no barriers).
// grid (S/128, NH*KSPLIT, B), block 256 (4 waves), 4 blocks/CU.
__global__ __launch_bounds__(256, 4) void attn_kernel(const ushort* __restrict__ Qn,
                                                      const ushort* __restrict__ Kn,
                                                      const ushort* __restrict__ Vt,
                                                      float* __restrict__ accP,
                                                      float* __restrict__ lP) {
  const int b = blockIdx.z;
  const int h = blockIdx.y & 7, kp = blockIdx.y >> 3;
  const int wid = threadIdx.x >> 6, lane = threadIdx.x & 63;
  const int col = lane & 15, quad = lane >> 4;
  const int q0 = blockIdx.x * 128 + wid * 32;

  __shared__ ushort P_lds[4][32][PW];
  ushort(*__restrict__ P)[PW] = P_lds[wid];

  const ushort* Qh = Qn + (size_t)(b * NH + h) * S * HD;
  const ushort* Kh = Kn + (size_t)(b * NH + h) * S * HD;
  const ushort* Vh = Vt + (size_t)(b * NH + h) * HD * S;

  bf16x8 qf[2];
  #pragma unroll
  for (int nt = 0; nt < 2; nt++)
    qf[nt] = *(const bf16x8*)&Qh[(size_t)(q0 + nt * 16 + col) * HD + quad * 8];

  const u16x8 ou = {0x3F80, 0x3F80, 0x3F80, 0x3F80, 0x3F80, 0x3F80, 0x3F80, 0x3F80};
  const bf16x8 ones = __builtin_bit_cast(bf16x8, ou);
  const f32x4 z = {0.f, 0.f, 0.f, 0.f};

  f32x4 acc[2][2] = {};
  f32x4 accl[2] = {};

  const int kt0 = kp * (S / KSPLIT), kt1 = kt0 + S / KSPLIT;
  bf16x8 kf[4];
  #pragma unroll
  for (int mt = 0; mt < 4; mt++)
    kf[mt] = *(const bf16x8*)&Kh[(size_t)(kt0 + mt * 16 + col) * HD + quad * 8];

  for (int kt = kt0; kt < kt1; kt += 64) {
    bf16x8 vf[2][2];
    #pragma unroll
    for (int dt = 0; dt < 2; dt++)
      #pragma unroll
      for (int kc = 0; kc < 2; kc++)
        vf[dt][kc] = *(const bf16x8*)&Vh[(size_t)(dt * 16 + col) * S + kt + kc * 32 + quad * 8];

    #pragma unroll
    for (int mt = 0; mt < 4; mt++) {
      f32x4 s0 = __builtin_amdgcn_mfma_f32_16x16x32_bf16(kf[mt], qf[0], z, 0, 0, 0);
      f32x4 s1 = __builtin_amdgcn_mfma_f32_16x16x32_bf16(kf[mt], qf[1], z, 0, 0, 0);
      // prefetch next tile's K frags (reads past partition end stay inside
      // the workspace -> harmless garbage, never used on last iter)
      kf[mt] = *(const bf16x8*)&Kh[(size_t)(kt + 64 + mt * 16 + col) * HD + quad * 8];
      uint2 w0, w1;
      w0.x = pack2bf(__builtin_amdgcn_exp2f(s0[0]), __builtin_amdgcn_exp2f(s0[1]));
      w0.y = pack2bf(__builtin_amdgcn_exp2f(s0[2]), __builtin_amdgcn_exp2f(s0[3]));
      w1.x = pack2bf(__builtin_amdgcn_exp2f(s1[0]), __builtin_amdgcn_exp2f(s1[1]));
      w1.y = pack2bf(__builtin_amdgcn_exp2f(s1[2]), __builtin_amdgcn_exp2f(s1[3]));
      *(uint2*)&P[col][mt * 16 + quad * 4] = w0;
      *(uint2*)&P[16 + col][mt * 16 + quad * 4] = w1;
    }

    #pragma unroll
    for (int nt = 0; nt < 2; nt++)
      #pragma unroll
      for (int kc = 0; kc < 2; kc++) {
        bf16x8 pf = *(const bf16x8*)&P[nt * 16 + col][kc * 32 + quad * 8];
        accl[nt] = __builtin_amdgcn_mfma_f32_16x16x32_bf16(ones, pf, accl[nt], 0, 0, 0);
        #pragma unroll
        for (int dt = 0; dt < 2; dt++)
          acc[dt][nt] = __builtin_amdgcn_mfma_f32_16x16x32_bf16(vf[dt][kc], pf, acc[dt][nt], 0, 0, 0);
      }
  }

  float* ap = accP + ((size_t)((kp * 2 + b) * NH + h)) * S * HD;
  #pragma unroll
  for (int dt = 0; dt < 2; dt++)
    #pragma unroll
    for (int nt = 0; nt < 2; nt++) {
      float4 u;
      u.x = acc[dt][nt][0];
      u.y = acc[dt][nt][1];
      u.z = acc[dt][nt][2];
      u.w = acc[dt][nt][3];
      *(float4*)&ap[(size_t)(q0 + nt * 16 + col) * HD + dt * 16 + quad * 4] = u;
    }
  if (quad == 0) {
    #pragma unroll
    for (int nt = 0; nt < 2; nt++)
      lP[((size_t)((kp * 2 + b) * NH + h)) * S + q0 + nt * 16 + col] = accl[nt][0];
  }
}

// ---------------- conv2 fused with K-split combine ---------------------------
// OUT[b][m][s] fp32 with mp_add. B-fragments built in-register from the
// attention partials: y[q][k] = (accP0 + accP1)[q][h][d] / (l0+l1)[h][q],
// h = k/32, d = k mod 32 -> normalize + bf16-pack replaces the combine kernel
// and the Yt round-trip. grid (S/128, CIN/64, B), block 256 (4 waves).
__global__ __launch_bounds__(256) void conv2_fused_kernel(const ushort* __restrict__ W,
                                                          const float* __restrict__ accP,
                                                          const float* __restrict__ lP,
                                                          const float* __restrict__ RES,
                                                          float* __restrict__ OUT) {
  const int b = blockIdx.z;
  const int wid = threadIdx.x >> 6, lane = threadIdx.x & 63;
  const int col = lane & 15, quad = lane >> 4;
  const int m0 = blockIdx.y * 64 + (wid >> 1) * 32;
  const int n0 = blockIdx.x * 128 + (wid & 1) * 64;
  f32x4 acc[2][4] = {};
  #pragma unroll
  for (int k0 = 0; k0 < CIN; k0 += 32) {
    const int h = k0 >> 5;
    const size_t hb0 = ((size_t)(b * NH + h)) * S;
    const size_t hb1 = ((size_t)((2 + b) * NH + h)) * S;
    bf16x8 af[2], bf[4];
    #pragma unroll
    for (int mi = 0; mi < 2; mi++)
      af[mi] = *(const bf16x8*)&W[(size_t)(m0 + mi * 16 + col) * CIN + k0 + quad * 8];
    #pragma unroll
    for (int ni = 0; ni < 4; ni++) {
      const int q = n0 + ni * 16 + col;
      const float4 a0 = *(const float4*)&accP[(hb0 + q) * HD + quad * 8];
      const float4 a0h = *(const float4*)&accP[(hb0 + q) * HD + quad * 8 + 4];
      const float4 a1 = *(const float4*)&accP[(hb1 + q) * HD + quad * 8];
      const float4 a1h = *(const float4*)&accP[(hb1 + q) * HD + quad * 8 + 4];
      const float rl = 1.0f / (lP[hb0 + q] + lP[hb1 + q]);
      uint4 wv;
      wv.x = pack2bf((a0.x + a1.x) * rl, (a0.y + a1.y) * rl);
      wv.y = pack2bf((a0.z + a1.z) * rl, (a0.w + a1.w) * rl);
      wv.z = pack2bf((a0h.x + a1h.x) * rl, (a0h.y + a1h.y) * rl);
      wv.w = pack2bf((a0h.z + a1h.z) * rl, (a0h.w + a1h.w) * rl);
      bf[ni] = __builtin_bit_cast(bf16x8, wv);
    }
    #pragma unroll
    for (int mi = 0; mi < 2; mi++)
      #pragma unroll
      for (int ni = 0; ni < 4; ni++)
        acc[mi][ni] = __builtin_amdgcn_mfma_f32_16x16x32_bf16(af[mi], bf[ni], acc[mi][ni], 0, 0, 0);
  }
  const float tc = 0.3f, om = 0.7f, inv = 1.3130643285972254f;
  #pragma unroll
  for (int mi = 0; mi < 2; mi++)
    #pragma unroll
    for (int ni = 0; ni < 4; ni++)
      #pragma unroll
      for (int r = 0; r < 4; r++) {
        const size_t idx = ((size_t)(b * CIN + m0 + mi * 16 + quad * 4 + r)) * S + n0 + ni * 16 + col;
        OUT[idx] = (om * RES[idx] + tc * acc[mi][ni][r]) * inv;
      }
}

// ---------------- launch ----------------
extern "C" void kernel_launch(void* const* d_in, const int* in_sizes, int n_in,
                              void* d_out, int out_size, void* d_ws, size_t ws_size,
                              hipStream_t stream) {
  const float* x = (const float*)d_in[0];
  const float* w_qkv = (const float*)d_in[1];
  const float* w_out = (const float*)d_in[2];
  float* out = (float*)d_out;

  ushort* p = (ushort*)d_ws;
  ushort* wqb = p; p += (size_t)C3 * CIN;
  ushort* wob = p; p += (size_t)CIN * CIN;
  ushort* Qn = p; p += (size_t)2 * NH * S * HD;
  ushort* Kn = p; p += (size_t)2 * NH * S * HD;
  ushort* Vt = p; p += (size_t)2 * NH * S * HD;
  // Region R: Xt (4 MB) + qkvT (12.6 MB) die after pixnorm; accP fp32
  // (KSPLIT*2*8*4096*32 floats = 16.78 MB) aliases the same region exactly.
  ushort* R = p; p += (size_t)2 * S * CIN + (size_t)2 * S * C3;
  ushort* Xt = R;
  ushort* qkvT = R + (size_t)2 * S * CIN;
  float* accP = (float*)R;
  float* lP = (float*)p;  // KSPLIT*2*8*4096 floats = 0.5 MB

  wnorm_kernel<<<(C3 + CIN) / 4, 256, 0, stream>>>(w_qkv, w_out, wqb, wob);
  xt_kernel<<<dim3(S / 64, CIN / 64, 2), 256, 0, stream>>>(x, Xt);
  conv1_kernel<<<dim3(S / 128, C3 / 64, 2), 256, 0, stream>>>(wqb, Xt, qkvT);
  pixnorm_kernel<<<dim3(S / 256, 24, 2), 256, 0, stream>>>(qkvT, Qn, Kn, Vt);
  attn_kernel<<<dim3(S / 128, NH * KSPLIT, 2), 256, 0, stream>>>(Qn, Kn, Vt, accP, lP);
  conv2_fused_kernel<<<dim3(S / 128, CIN / 64, 2), 256, 0, stream>>>(wob, accP, lP, x, out);
}

// Round 9
// 205.666 us; speedup vs baseline: 1.4077x; 1.0350x over previous
//
#include <hip/hip_runtime.h>
#include <hip/hip_bf16.h>
#include <math.h>

#define S 4096
#define CIN 256
#define C3 768
#define NH 8
#define HD 32
#define KSPLIT 2
#define PW 72

static constexpr float EPS = 1e-4f;

typedef __attribute__((ext_vector_type(8))) __bf16 bf16x8;
typedef __attribute__((ext_vector_type(4))) float f32x4;
typedef __attribute__((ext_vector_type(8))) unsigned short u16x8;

static inline __device__ ushort f2bf(float f) {  // RN-even
  unsigned u = __float_as_uint(f);
  return (ushort)((u + 0x7fffu + ((u >> 16) & 1u)) >> 16);
}
static inline __device__ float bf2f(ushort u) {
  return __uint_as_float(((unsigned)u) << 16);
}
// pack two floats to bf16x2 (round-by-add, 3 VALU ops)
static inline __device__ unsigned pack2bf(float lo, float hi) {
  unsigned a = __float_as_uint(lo) + 0x8000u;
  unsigned b = __float_as_uint(hi) + 0x8000u;
  return __builtin_amdgcn_perm(b, a, 0x07060302);
}

// ---------------- weight norm (both weights, one launch) ---------------------
__global__ __launch_bounds__(256) void wnorm_kernel(const float* __restrict__ w_qkv,
                                                    const float* __restrict__ w_out,
                                                    ushort* __restrict__ wqb,
                                                    ushort* __restrict__ wob) {
  const int row = blockIdx.x * 4 + (threadIdx.x >> 6);
  const int lane = threadIdx.x & 63;
  const bool is_q = row < C3;
  const float* wr = (is_q ? w_qkv + (size_t)row * CIN : w_out + (size_t)(row - C3) * CIN);
  float v0 = wr[lane], v1 = wr[lane + 64], v2 = wr[lane + 128], v3 = wr[lane + 192];
  float ss = v0 * v0 + v1 * v1 + v2 * v2 + v3 * v3;
  #pragma unroll
  for (int off = 32; off > 0; off >>= 1) ss += __shfl_down(ss, off, 64);
  ss = __shfl(ss, 0, 64);
  const float scale = 1.0f / (sqrtf(ss) + 16.0f * EPS);
  ushort* whr = (is_q ? wqb + (size_t)row * CIN : wob + (size_t)(row - C3) * CIN);
  whr[lane] = f2bf(v0 * scale);
  whr[lane + 64] = f2bf(v1 * scale);
  whr[lane + 128] = f2bf(v2 * scale);
  whr[lane + 192] = f2bf(v3 * scale);
}

// ---------------- X [b][c][s] fp32 -> Xt [b][s][c] bf16 ----------------------
__global__ __launch_bounds__(256) void xt_kernel(const float* __restrict__ X,
                                                 ushort* __restrict__ Xt) {
  const int b = blockIdx.z;
  const int s0 = blockIdx.x * 64, c0 = blockIdx.y * 64;
  __shared__ ushort T[64][72];
  const int tc = threadIdx.x >> 4;
  const int ts = threadIdx.x & 15;
  #pragma unroll
  for (int i = 0; i < 4; i++) {
    const float4 v = *(const float4*)&X[((size_t)(b * CIN + c0 + tc + 16 * i)) * S + s0 + ts * 4];
    ushort4 u;
    u.x = f2bf(v.x); u.y = f2bf(v.y); u.z = f2bf(v.z); u.w = f2bf(v.w);
    *(ushort4*)&T[tc + 16 * i][ts * 4] = u;
  }
  __syncthreads();
  #pragma unroll
  for (int i = 0; i < 4; i++) {
    const int sr = tc + 16 * i;
    ushort4 u;
    u.x = T[ts * 4 + 0][sr];
    u.y = T[ts * 4 + 1][sr];
    u.z = T[ts * 4 + 2][sr];
    u.w = T[ts * 4 + 3][sr];
    *(ushort4*)&Xt[((size_t)b * S + s0 + sr) * CIN + c0 + ts * 4] = u;
  }
}

// ---------------- MFMA 1x1 conv: OUT[m][n] = sum_k W[m][k] B[n][k] -----------
template <int MOUT, int MODE>
__global__ __launch_bounds__(256) void conv_mfma_kernel(const ushort* __restrict__ W,
                                                        const ushort* __restrict__ Bm,
                                                        void* __restrict__ OUTv,
                                                        const float* __restrict__ RES) {
  const int b = blockIdx.z;
  const int wid = threadIdx.x >> 6, lane = threadIdx.x & 63;
  const int col = lane & 15, quad = lane >> 4;
  const int m0 = blockIdx.y * 64 + (wid >> 1) * 32;
  const int n0 = blockIdx.x * 128 + (wid & 1) * 64;
  const ushort* Bb = Bm + (size_t)b * S * CIN;
  f32x4 acc[2][4] = {};
  #pragma unroll
  for (int k0 = 0; k0 < CIN; k0 += 32) {
    bf16x8 af[2], bf[4];
    #pragma unroll
    for (int mi = 0; mi < 2; mi++)
      af[mi] = *(const bf16x8*)&W[(size_t)(m0 + mi * 16 + col) * CIN + k0 + quad * 8];
    #pragma unroll
    for (int ni = 0; ni < 4; ni++)
      bf[ni] = *(const bf16x8*)&Bb[(size_t)(n0 + ni * 16 + col) * CIN + k0 + quad * 8];
    #pragma unroll
    for (int mi = 0; mi < 2; mi++)
      #pragma unroll
      for (int ni = 0; ni < 4; ni++)
        acc[mi][ni] = __builtin_amdgcn_mfma_f32_16x16x32_bf16(af[mi], bf[ni], acc[mi][ni], 0, 0, 0);
  }
  if (MODE == 0) {
    ushort* O = (ushort*)OUTv;
    #pragma unroll
    for (int mi = 0; mi < 2; mi++)
      #pragma unroll
      for (int ni = 0; ni < 4; ni++) {
        ushort4 u;
        u.x = f2bf(acc[mi][ni][0]);
        u.y = f2bf(acc[mi][ni][1]);
        u.z = f2bf(acc[mi][ni][2]);
        u.w = f2bf(acc[mi][ni][3]);
        *(ushort4*)&O[((size_t)b * S + n0 + ni * 16 + col) * MOUT + m0 + mi * 16 + quad * 4] = u;
      }
  } else {
    float* O = (float*)OUTv;
    const float tc = 0.3f, om = 0.7f, inv = 1.3130643285972254f;
    #pragma unroll
    for (int mi = 0; mi < 2; mi++)
      #pragma unroll
      for (int ni = 0; ni < 4; ni++)
        #pragma unroll
        for (int r = 0; r < 4; r++) {
          const size_t idx = ((size_t)(b * MOUT + m0 + mi * 16 + quad * 4 + r)) * S + n0 + ni * 16 + col;
          O[idx] = (om * RES[idx] + tc * acc[mi][ni][r]) * inv;
        }
  }
}

// ---------------- pixel norm + layout fan-out --------------------------------
// Q additionally pre-scaled by log2(e)/sqrt(32) so attention skips the mul.
__global__ __launch_bounds__(256) void pixnorm_kernel(const ushort* __restrict__ qkvT,
                                                      ushort* __restrict__ Qn,
                                                      ushort* __restrict__ Kn,
                                                      ushort* __restrict__ Vt) {
  const int b = blockIdx.z, g = blockIdx.y;
  const int s = blockIdx.x * 256 + threadIdx.x;
  const ushort* src = qkvT + ((size_t)b * S + s) * C3 + g * HD;
  float v[HD];
  float ss = 0.f;
  #pragma unroll
  for (int i = 0; i < 8; i++) {
    ushort4 u = *(const ushort4*)&src[i * 4];
    float f0 = bf2f(u.x), f1 = bf2f(u.y), f2 = bf2f(u.z), f3 = bf2f(u.w);
    v[i * 4 + 0] = f0; v[i * 4 + 1] = f1; v[i * 4 + 2] = f2; v[i * 4 + 3] = f3;
    ss += f0 * f0 + f1 * f1 + f2 * f2 + f3 * f3;
  }
  float r = rsqrtf(ss * (1.0f / HD) + EPS);
  if (g < 16) {
    if (g < 8) r *= 0.2550348190698169f;  // log2(e)/sqrt(32) folded into Q
    ushort* dst = (g < 8 ? Qn : Kn) + ((size_t)(b * NH + (g & 7)) * S + s) * HD;
    #pragma unroll
    for (int i = 0; i < 8; i++) {
      ushort4 u;
      u.x = f2bf(v[i * 4 + 0] * r);
      u.y = f2bf(v[i * 4 + 1] * r);
      u.z = f2bf(v[i * 4 + 2] * r);
      u.w = f2bf(v[i * 4 + 3] * r);
      *(ushort4*)&dst[i * 4] = u;
    }
  } else {
    ushort* dst = Vt + ((size_t)(b * NH + (g - 16)) * HD) * S + s;
    #pragma unroll
    for (int d = 0; d < HD; d++) dst[(size_t)d * S] = f2bf(v[d] * r);
  }
}

// ---------------- MFMA attention, K-split x2, read-early dbuf ----------------
// Fix for R6's failed pipelining: the loop now issues the CONSUME ds_reads of
// buf[p] FIRST (oldest DS ops), then the S-phase (MFMA->exp->pack->ds_write)
// for tile t+1 into buf[p^1], then PV MFMAs. The wait before PV is now
// lgkmcnt(#writes) rather than a full drain, so tile t+1's exp/pack/write
// chain overlaps tile t's PV MFMAs. Runtime-indexed buffers keep the
// compiler from reordering reads after writes.
// grid (S/128, NH*KSPLIT, B), block 256 (4 waves), 4 blocks/CU, no barriers.
__global__ __launch_bounds__(256, 4) void attn_kernel(const ushort* __restrict__ Qn,
                                                      const ushort* __restrict__ Kn,
                                                      const ushort* __restrict__ Vt,
                                                      float* __restrict__ accP,
                                                      float* __restrict__ lP) {
  const int b = blockIdx.z;
  const int h = blockIdx.y & 7, kp = blockIdx.y >> 3;
  const int wid = threadIdx.x >> 6, lane = threadIdx.x & 63;
  const int col = lane & 15, quad = lane >> 4;
  const int q0 = blockIdx.x * 128 + wid * 32;

  __shared__ ushort P_lds[2][4][32][PW];

  const ushort* Qh = Qn + (size_t)(b * NH + h) * S * HD;
  const ushort* Kh = Kn + (size_t)(b * NH + h) * S * HD;
  const ushort* Vh = Vt + (size_t)(b * NH + h) * HD * S;

  bf16x8 qf[2];
  #pragma unroll
  for (int nt = 0; nt < 2; nt++)
    qf[nt] = *(const bf16x8*)&Qh[(size_t)(q0 + nt * 16 + col) * HD + quad * 8];

  const u16x8 ou = {0x3F80, 0x3F80, 0x3F80, 0x3F80, 0x3F80, 0x3F80, 0x3F80, 0x3F80};
  const bf16x8 ones = __builtin_bit_cast(bf16x8, ou);
  const f32x4 z = {0.f, 0.f, 0.f, 0.f};

  f32x4 acc[2][2] = {};
  f32x4 accl[2] = {};

  const int kt0 = kp * (S / KSPLIT), kt1 = kt0 + S / KSPLIT;
  bf16x8 kf[4];
  #pragma unroll
  for (int mt = 0; mt < 4; mt++)
    kf[mt] = *(const bf16x8*)&Kh[(size_t)(kt0 + mt * 16 + col) * HD + quad * 8];

  // S-phase: scores for the tile whose K frags sit in kf -> exp -> pack ->
  // write PB; prefetch kf for tile KNEXT (overreads stay in workspace).
#define S_PHASE(PB, KNEXT)                                                             \
  {                                                                                    \
    _Pragma("unroll") for (int mt = 0; mt < 4; mt++) {                                 \
      f32x4 s0 = __builtin_amdgcn_mfma_f32_16x16x32_bf16(kf[mt], qf[0], z, 0, 0, 0);   \
      f32x4 s1 = __builtin_amdgcn_mfma_f32_16x16x32_bf16(kf[mt], qf[1], z, 0, 0, 0);   \
      kf[mt] = *(const bf16x8*)&Kh[(size_t)((KNEXT) + mt * 16 + col) * HD + quad * 8]; \
      uint2 w0, w1;                                                                    \
      w0.x = pack2bf(__builtin_amdgcn_exp2f(s0[0]), __builtin_amdgcn_exp2f(s0[1]));    \
      w0.y = pack2bf(__builtin_amdgcn_exp2f(s0[2]), __builtin_amdgcn_exp2f(s0[3]));    \
      w1.x = pack2bf(__builtin_amdgcn_exp2f(s1[0]), __builtin_amdgcn_exp2f(s1[1]));    \
      w1.y = pack2bf(__builtin_amdgcn_exp2f(s1[2]), __builtin_amdgcn_exp2f(s1[3]));    \
      *(uint2*)&PB[col][mt * 16 + quad * 4] = w0;                                      \
      *(uint2*)&PB[16 + col][mt * 16 + quad * 4] = w1;                                 \
    }                                                                                  \
  }

  // prologue: P for first tile -> buf0 (kf advances to kt0+64)
  {
    ushort(*__restrict__ PB)[PW] = P_lds[0][wid];
    S_PHASE(PB, kt0 + 64);
  }

  int p = 0;
  for (int kt = kt0; kt < kt1; kt += 64) {
    ushort(*__restrict__ PC)[PW] = P_lds[p][wid];      // consume
    ushort(*__restrict__ PN)[PW] = P_lds[p ^ 1][wid];  // produce

    // (1) consume-reads FIRST: oldest DS ops of this iteration
    bf16x8 pf[2][2];
    #pragma unroll
    for (int nt = 0; nt < 2; nt++)
      #pragma unroll
      for (int kc = 0; kc < 2; kc++)
        pf[nt][kc] = *(const bf16x8*)&PC[nt * 16 + col][kc * 32 + quad * 8];

    // (2) V loads for this tile (vmcnt, hides under S-phase)
    bf16x8 vf[2][2];
    #pragma unroll
    for (int dt = 0; dt < 2; dt++)
      #pragma unroll
      for (int kc = 0; kc < 2; kc++)
        vf[dt][kc] = *(const bf16x8*)&Vh[(size_t)(dt * 16 + col) * S + kt + kc * 32 + quad * 8];

    // (3) produce P for tile kt+64 (writes are younger than the reads above,
    //     so the PV wait below need not drain them)
    if (kt + 64 < kt1) {
      S_PHASE(PN, kt + 128);
    }

    // (4) PV for tile kt
    #pragma unroll
    for (int nt = 0; nt < 2; nt++)
      #pragma unroll
      for (int kc = 0; kc < 2; kc++) {
        accl[nt] = __builtin_amdgcn_mfma_f32_16x16x32_bf16(ones, pf[nt][kc], accl[nt], 0, 0, 0);
        #pragma unroll
        for (int dt = 0; dt < 2; dt++)
          acc[dt][nt] = __builtin_amdgcn_mfma_f32_16x16x32_bf16(vf[dt][kc], pf[nt][kc], acc[dt][nt], 0, 0, 0);
      }
    p ^= 1;
  }
#undef S_PHASE

  float* ap = accP + ((size_t)((kp * 2 + b) * NH + h)) * S * HD;
  #pragma unroll
  for (int dt = 0; dt < 2; dt++)
    #pragma unroll
    for (int nt = 0; nt < 2; nt++) {
      float4 u;
      u.x = acc[dt][nt][0];
      u.y = acc[dt][nt][1];
      u.z = acc[dt][nt][2];
      u.w = acc[dt][nt][3];
      *(float4*)&ap[(size_t)(q0 + nt * 16 + col) * HD + dt * 16 + quad * 4] = u;
    }
  if (quad == 0) {
    #pragma unroll
    for (int nt = 0; nt < 2; nt++)
      lP[((size_t)((kp * 2 + b) * NH + h)) * S + q0 + nt * 16 + col] = accl[nt][0];
  }
}

// ---------------- combine K-split partials -> Yt [b][s][256] bf16 ------------
// one thread per (b,h,q,dg): 2*8*4096*8 = 524288 threads = 2048 blocks.
__global__ __launch_bounds__(256) void combine_kernel(const float* __restrict__ accP,
                                                      const float* __restrict__ lP,
                                                      ushort* __restrict__ Yt) {
  const int tid = blockIdx.x * 256 + threadIdx.x;
  const int dg = tid & 7;
  const int q = (tid >> 3) & (S - 1);
  const int h = (tid >> 15) & 7;
  const int b = tid >> 18;
  const size_t i0 = ((size_t)(b * NH + h)) * S + q;
  const size_t part = (size_t)2 * NH * S;
  float sx = 0.f, sy = 0.f, sz = 0.f, sw = 0.f, L = 0.f;
  #pragma unroll
  for (int p = 0; p < KSPLIT; p++) {
    const float4 a = *(const float4*)&accP[(size_t)p * part * HD + i0 * HD + dg * 4];
    sx += a.x; sy += a.y; sz += a.z; sw += a.w;
    L += lP[(size_t)p * part + i0];
  }
  const float rl = 1.0f / L;
  ushort4 o;
  o.x = f2bf(sx * rl);
  o.y = f2bf(sy * rl);
  o.z = f2bf(sz * rl);
  o.w = f2bf(sw * rl);
  *(ushort4*)&Yt[((size_t)b * S + q) * CIN + h * HD + dg * 4] = o;
}

// ---------------- launch ----------------
extern "C" void kernel_launch(void* const* d_in, const int* in_sizes, int n_in,
                              void* d_out, int out_size, void* d_ws, size_t ws_size,
                              hipStream_t stream) {
  const float* x = (const float*)d_in[0];
  const float* w_qkv = (const float*)d_in[1];
  const float* w_out = (const float*)d_in[2];
  float* out = (float*)d_out;

  ushort* p = (ushort*)d_ws;
  ushort* wqb = p; p += (size_t)C3 * CIN;
  ushort* wob = p; p += (size_t)CIN * CIN;
  ushort* Qn = p; p += (size_t)2 * NH * S * HD;
  ushort* Kn = p; p += (size_t)2 * NH * S * HD;
  ushort* Vt = p; p += (size_t)2 * NH * S * HD;
  ushort* Yt = p; p += (size_t)2 * S * CIN;
  // Region R: Xt (4 MB) + qkvT (12.6 MB) die after pixnorm; accP fp32
  // (KSPLIT*2*8*4096*32 floats = 16.78 MB) aliases the same region exactly.
  ushort* R = p; p += (size_t)2 * S * CIN + (size_t)2 * S * C3;
  ushort* Xt = R;
  ushort* qkvT = R + (size_t)2 * S * CIN;
  float* accP = (float*)R;
  float* lP = (float*)p;  // KSPLIT*2*8*4096 floats = 0.5 MB

  wnorm_kernel<<<(C3 + CIN) / 4, 256, 0, stream>>>(w_qkv, w_out, wqb, wob);
  xt_kernel<<<dim3(S / 64, CIN / 64, 2), 256, 0, stream>>>(x, Xt);
  conv_mfma_kernel<C3, 0><<<dim3(S / 128, C3 / 64, 2), 256, 0, stream>>>(wqb, Xt, qkvT, nullptr);
  pixnorm_kernel<<<dim3(S / 256, 24, 2), 256, 0, stream>>>(qkvT, Qn, Kn, Vt);
  attn_kernel<<<dim3(S / 128, NH * KSPLIT, 2), 256, 0, stream>>>(Qn, Kn, Vt, accP, lP);
  combine_kernel<<<2048, 256, 0, stream>>>(accP, lP, Yt);
  conv_mfma_kernel<CIN, 1><<<dim3(S / 128, CIN / 64, 2), 256, 0, stream>>>(wob, Yt, out, x);
}

// Round 10
// 195.672 us; speedup vs baseline: 1.4796x; 1.0511x over previous
//
#include <hip/hip_runtime.h>
#include <hip/hip_bf16.h>
#include <math.h>

#define S 4096
#define CIN 256
#define C3 768
#define NH 8
#define HD 32
#define KSPLIT 2
#define PW 72

static constexpr float EPS = 1e-4f;

typedef __attribute__((ext_vector_type(8))) __bf16 bf16x8;
typedef __attribute__((ext_vector_type(4))) float f32x4;
typedef __attribute__((ext_vector_type(8))) unsigned short u16x8;

static inline __device__ ushort f2bf(float f) {  // RN-even
  unsigned u = __float_as_uint(f);
  return (ushort)((u + 0x7fffu + ((u >> 16) & 1u)) >> 16);
}
// pack two floats to bf16x2 (round-by-add, 3 VALU ops)
static inline __device__ unsigned pack2bf(float lo, float hi) {
  unsigned a = __float_as_uint(lo) + 0x8000u;
  unsigned b = __float_as_uint(hi) + 0x8000u;
  return __builtin_amdgcn_perm(b, a, 0x07060302);
}

// ---------------- weight norm (both weights, one launch) ---------------------
__global__ __launch_bounds__(256) void wnorm_kernel(const float* __restrict__ w_qkv,
                                                    const float* __restrict__ w_out,
                                                    ushort* __restrict__ wqb,
                                                    ushort* __restrict__ wob) {
  const int row = blockIdx.x * 4 + (threadIdx.x >> 6);
  const int lane = threadIdx.x & 63;
  const bool is_q = row < C3;
  const float* wr = (is_q ? w_qkv + (size_t)row * CIN : w_out + (size_t)(row - C3) * CIN);
  float v0 = wr[lane], v1 = wr[lane + 64], v2 = wr[lane + 128], v3 = wr[lane + 192];
  float ss = v0 * v0 + v1 * v1 + v2 * v2 + v3 * v3;
  #pragma unroll
  for (int off = 32; off > 0; off >>= 1) ss += __shfl_down(ss, off, 64);
  ss = __shfl(ss, 0, 64);
  const float scale = 1.0f / (sqrtf(ss) + 16.0f * EPS);
  ushort* whr = (is_q ? wqb + (size_t)row * CIN : wob + (size_t)(row - C3) * CIN);
  whr[lane] = f2bf(v0 * scale);
  whr[lane + 64] = f2bf(v1 * scale);
  whr[lane + 128] = f2bf(v2 * scale);
  whr[lane + 192] = f2bf(v3 * scale);
}

// ---------------- X [b][c][s] fp32 -> Xt [b][s][c] bf16 ----------------------
__global__ __launch_bounds__(256) void xt_kernel(const float* __restrict__ X,
                                                 ushort* __restrict__ Xt) {
  const int b = blockIdx.z;
  const int s0 = blockIdx.x * 64, c0 = blockIdx.y * 64;
  __shared__ ushort T[64][72];
  const int tc = threadIdx.x >> 4;
  const int ts = threadIdx.x & 15;
  #pragma unroll
  for (int i = 0; i < 4; i++) {
    const float4 v = *(const float4*)&X[((size_t)(b * CIN + c0 + tc + 16 * i)) * S + s0 + ts * 4];
    ushort4 u;
    u.x = f2bf(v.x); u.y = f2bf(v.y); u.z = f2bf(v.z); u.w = f2bf(v.w);
    *(ushort4*)&T[tc + 16 * i][ts * 4] = u;
  }
  __syncthreads();
  #pragma unroll
  for (int i = 0; i < 4; i++) {
    const int sr = tc + 16 * i;
    ushort4 u;
    u.x = T[ts * 4 + 0][sr];
    u.y = T[ts * 4 + 1][sr];
    u.z = T[ts * 4 + 2][sr];
    u.w = T[ts * 4 + 3][sr];
    *(ushort4*)&Xt[((size_t)b * S + s0 + sr) * CIN + c0 + ts * 4] = u;
  }
}

// ---------------- conv1 fused with pixel-norm + layout fan-out ---------------
// QKV GEMM where each wave's 32(m) x 64(n) tile is exactly one 32-channel head
// group x 64 pixels. Pixel norm's channel reduction = in-register acc^2 sum +
// shfl_xor(16,32) across quads (fp32 domain, pre-bf16: more accurate than a
// separate post-bf16 pass). Writes Qn/Kn [bh][s][32] (Q pre-scaled by
// log2(e)/sqrt(32)) and Vt [bh][d][S] directly -- no qkvT materialization,
// no pixnorm kernel. grid (S/128, C3/64, B), block 256 (4 waves).
__global__ __launch_bounds__(256) void conv1_fused_kernel(const ushort* __restrict__ W,
                                                          const ushort* __restrict__ Bm,
                                                          ushort* __restrict__ Qn,
                                                          ushort* __restrict__ Kn,
                                                          ushort* __restrict__ Vt) {
  const int b = blockIdx.z;
  const int wid = threadIdx.x >> 6, lane = threadIdx.x & 63;
  const int col = lane & 15, quad = lane >> 4;
  const int m0 = blockIdx.y * 64 + (wid >> 1) * 32;  // 32-aligned: one head group
  const int n0 = blockIdx.x * 128 + (wid & 1) * 64;
  const ushort* Bb = Bm + (size_t)b * S * CIN;
  f32x4 acc[2][4] = {};
  #pragma unroll
  for (int k0 = 0; k0 < CIN; k0 += 32) {
    bf16x8 af[2], bf[4];
    #pragma unroll
    for (int mi = 0; mi < 2; mi++)
      af[mi] = *(const bf16x8*)&W[(size_t)(m0 + mi * 16 + col) * CIN + k0 + quad * 8];
    #pragma unroll
    for (int ni = 0; ni < 4; ni++)
      bf[ni] = *(const bf16x8*)&Bb[(size_t)(n0 + ni * 16 + col) * CIN + k0 + quad * 8];
    #pragma unroll
    for (int mi = 0; mi < 2; mi++)
      #pragma unroll
      for (int ni = 0; ni < 4; ni++)
        acc[mi][ni] = __builtin_amdgcn_mfma_f32_16x16x32_bf16(af[mi], bf[ni], acc[mi][ni], 0, 0, 0);
  }

  const int g = m0 >> 5;   // 0..23: group; 0-7 Q, 8-15 K, 16-23 V
  const int h = g & 7;
  float rn[4];
  #pragma unroll
  for (int ni = 0; ni < 4; ni++) {
    float ss = 0.f;
    #pragma unroll
    for (int mi = 0; mi < 2; mi++)
      #pragma unroll
      for (int r = 0; r < 4; r++) ss += acc[mi][ni][r] * acc[mi][ni][r];
    ss += __shfl_xor(ss, 16, 64);
    ss += __shfl_xor(ss, 32, 64);
    rn[ni] = rsqrtf(ss * (1.0f / HD) + EPS);
    if (g < 8) rn[ni] *= 0.2550348190698169f;  // log2(e)/sqrt(32) folded into Q
  }

  if (g < 16) {
    ushort* dst = (g < 8 ? Qn : Kn) + (size_t)(b * NH + h) * S * HD;
    #pragma unroll
    for (int mi = 0; mi < 2; mi++)
      #pragma unroll
      for (int ni = 0; ni < 4; ni++) {
        ushort4 u;
        u.x = f2bf(acc[mi][ni][0] * rn[ni]);
        u.y = f2bf(acc[mi][ni][1] * rn[ni]);
        u.z = f2bf(acc[mi][ni][2] * rn[ni]);
        u.w = f2bf(acc[mi][ni][3] * rn[ni]);
        *(ushort4*)&dst[(size_t)(n0 + ni * 16 + col) * HD + mi * 16 + quad * 4] = u;
      }
  } else {
    ushort* dst = Vt + (size_t)(b * NH + h) * HD * S;
    #pragma unroll
    for (int mi = 0; mi < 2; mi++)
      #pragma unroll
      for (int ni = 0; ni < 4; ni++)
        #pragma unroll
        for (int r = 0; r < 4; r++)
          dst[(size_t)(mi * 16 + quad * 4 + r) * S + n0 + ni * 16 + col] =
              f2bf(acc[mi][ni][r] * rn[ni]);
  }
}

// ---------------- MFMA attention, 32 q/wave, K-split x2 (R4 proven) ----------
// S^T = K.Q^T (Q pre-scaled -> exp2 direct); P bf16 via v_perm; l via ones-A
// MFMA; PV as out^T = V^T.P^T through per-wave LDS (no barriers).
// grid (S/128, NH*KSPLIT, B), block 256 (4 waves), 4 blocks/CU.
__global__ __launch_bounds__(256, 4) void attn_kernel(const ushort* __restrict__ Qn,
                                                      const ushort* __restrict__ Kn,
                                                      const ushort* __restrict__ Vt,
                                                      float* __restrict__ accP,
                                                      float* __restrict__ lP) {
  const int b = blockIdx.z;
  const int h = blockIdx.y & 7, kp = blockIdx.y >> 3;
  const int wid = threadIdx.x >> 6, lane = threadIdx.x & 63;
  const int col = lane & 15, quad = lane >> 4;
  const int q0 = blockIdx.x * 128 + wid * 32;

  __shared__ ushort P_lds[4][32][PW];
  ushort(*__restrict__ P)[PW] = P_lds[wid];

  const ushort* Qh = Qn + (size_t)(b * NH + h) * S * HD;
  const ushort* Kh = Kn + (size_t)(b * NH + h) * S * HD;
  const ushort* Vh = Vt + (size_t)(b * NH + h) * HD * S;

  bf16x8 qf[2];
  #pragma unroll
  for (int nt = 0; nt < 2; nt++)
    qf[nt] = *(const bf16x8*)&Qh[(size_t)(q0 + nt * 16 + col) * HD + quad * 8];

  const u16x8 ou = {0x3F80, 0x3F80, 0x3F80, 0x3F80, 0x3F80, 0x3F80, 0x3F80, 0x3F80};
  const bf16x8 ones = __builtin_bit_cast(bf16x8, ou);
  const f32x4 z = {0.f, 0.f, 0.f, 0.f};

  f32x4 acc[2][2] = {};
  f32x4 accl[2] = {};

  const int kt0 = kp * (S / KSPLIT), kt1 = kt0 + S / KSPLIT;
  bf16x8 kf[4];
  #pragma unroll
  for (int mt = 0; mt < 4; mt++)
    kf[mt] = *(const bf16x8*)&Kh[(size_t)(kt0 + mt * 16 + col) * HD + quad * 8];

  for (int kt = kt0; kt < kt1; kt += 64) {
    bf16x8 vf[2][2];
    #pragma unroll
    for (int dt = 0; dt < 2; dt++)
      #pragma unroll
      for (int kc = 0; kc < 2; kc++)
        vf[dt][kc] = *(const bf16x8*)&Vh[(size_t)(dt * 16 + col) * S + kt + kc * 32 + quad * 8];

    #pragma unroll
    for (int mt = 0; mt < 4; mt++) {
      f32x4 s0 = __builtin_amdgcn_mfma_f32_16x16x32_bf16(kf[mt], qf[0], z, 0, 0, 0);
      f32x4 s1 = __builtin_amdgcn_mfma_f32_16x16x32_bf16(kf[mt], qf[1], z, 0, 0, 0);
      // prefetch next tile's K frags (overreads stay inside the workspace)
      kf[mt] = *(const bf16x8*)&Kh[(size_t)(kt + 64 + mt * 16 + col) * HD + quad * 8];
      uint2 w0, w1;
      w0.x = pack2bf(__builtin_amdgcn_exp2f(s0[0]), __builtin_amdgcn_exp2f(s0[1]));
      w0.y = pack2bf(__builtin_amdgcn_exp2f(s0[2]), __builtin_amdgcn_exp2f(s0[3]));
      w1.x = pack2bf(__builtin_amdgcn_exp2f(s1[0]), __builtin_amdgcn_exp2f(s1[1]));
      w1.y = pack2bf(__builtin_amdgcn_exp2f(s1[2]), __builtin_amdgcn_exp2f(s1[3]));
      *(uint2*)&P[col][mt * 16 + quad * 4] = w0;
      *(uint2*)&P[16 + col][mt * 16 + quad * 4] = w1;
    }

    #pragma unroll
    for (int nt = 0; nt < 2; nt++)
      #pragma unroll
      for (int kc = 0; kc < 2; kc++) {
        bf16x8 pf = *(const bf16x8*)&P[nt * 16 + col][kc * 32 + quad * 8];
        accl[nt] = __builtin_amdgcn_mfma_f32_16x16x32_bf16(ones, pf, accl[nt], 0, 0, 0);
        #pragma unroll
        for (int dt = 0; dt < 2; dt++)
          acc[dt][nt] = __builtin_amdgcn_mfma_f32_16x16x32_bf16(vf[dt][kc], pf, acc[dt][nt], 0, 0, 0);
      }
  }

  float* ap = accP + ((size_t)((kp * 2 + b) * NH + h)) * S * HD;
  #pragma unroll
  for (int dt = 0; dt < 2; dt++)
    #pragma unroll
    for (int nt = 0; nt < 2; nt++) {
      float4 u;
      u.x = acc[dt][nt][0];
      u.y = acc[dt][nt][1];
      u.z = acc[dt][nt][2];
      u.w = acc[dt][nt][3];
      *(float4*)&ap[(size_t)(q0 + nt * 16 + col) * HD + dt * 16 + quad * 4] = u;
    }
  if (quad == 0) {
    #pragma unroll
    for (int nt = 0; nt < 2; nt++)
      lP[((size_t)((kp * 2 + b) * NH + h)) * S + q0 + nt * 16 + col] = accl[nt][0];
  }
}

// ---------------- combine K-split partials -> Yt [b][s][256] bf16 ------------
// one thread per (b,h,q,dg): 2*8*4096*8 = 524288 threads = 2048 blocks.
__global__ __launch_bounds__(256) void combine_kernel(const float* __restrict__ accP,
                                                      const float* __restrict__ lP,
                                                      ushort* __restrict__ Yt) {
  const int tid = blockIdx.x * 256 + threadIdx.x;
  const int dg = tid & 7;
  const int q = (tid >> 3) & (S - 1);
  const int h = (tid >> 15) & 7;
  const int b = tid >> 18;
  const size_t i0 = ((size_t)(b * NH + h)) * S + q;
  const size_t part = (size_t)2 * NH * S;
  float sx = 0.f, sy = 0.f, sz = 0.f, sw = 0.f, L = 0.f;
  #pragma unroll
  for (int p = 0; p < KSPLIT; p++) {
    const float4 a = *(const float4*)&accP[(size_t)p * part * HD + i0 * HD + dg * 4];
    sx += a.x; sy += a.y; sz += a.z; sw += a.w;
    L += lP[(size_t)p * part + i0];
  }
  const float rl = 1.0f / L;
  ushort4 o;
  o.x = f2bf(sx * rl);
  o.y = f2bf(sy * rl);
  o.z = f2bf(sz * rl);
  o.w = f2bf(sw * rl);
  *(ushort4*)&Yt[((size_t)b * S + q) * CIN + h * HD + dg * 4] = o;
}

// ---------------- conv2: OUT[b][m][s] fp32 = Wo . Yt, fused mp_add -----------
__global__ __launch_bounds__(256) void conv2_kernel(const ushort* __restrict__ W,
                                                    const ushort* __restrict__ Bm,
                                                    const float* __restrict__ RES,
                                                    float* __restrict__ OUT) {
  const int b = blockIdx.z;
  const int wid = threadIdx.x >> 6, lane = threadIdx.x & 63;
  const int col = lane & 15, quad = lane >> 4;
  const int m0 = blockIdx.y * 64 + (wid >> 1) * 32;
  const int n0 = blockIdx.x * 128 + (wid & 1) * 64;
  const ushort* Bb = Bm + (size_t)b * S * CIN;
  f32x4 acc[2][4] = {};
  #pragma unroll
  for (int k0 = 0; k0 < CIN; k0 += 32) {
    bf16x8 af[2], bf[4];
    #pragma unroll
    for (int mi = 0; mi < 2; mi++)
      af[mi] = *(const bf16x8*)&W[(size_t)(m0 + mi * 16 + col) * CIN + k0 + quad * 8];
    #pragma unroll
    for (int ni = 0; ni < 4; ni++)
      bf[ni] = *(const bf16x8*)&Bb[(size_t)(n0 + ni * 16 + col) * CIN + k0 + quad * 8];
    #pragma unroll
    for (int mi = 0; mi < 2; mi++)
      #pragma unroll
      for (int ni = 0; ni < 4; ni++)
        acc[mi][ni] = __builtin_amdgcn_mfma_f32_16x16x32_bf16(af[mi], bf[ni], acc[mi][ni], 0, 0, 0);
  }
  const float tc = 0.3f, om = 0.7f, inv = 1.3130643285972254f;
  #pragma unroll
  for (int mi = 0; mi < 2; mi++)
    #pragma unroll
    for (int ni = 0; ni < 4; ni++)
      #pragma unroll
      for (int r = 0; r < 4; r++) {
        const size_t idx = ((size_t)(b * CIN + m0 + mi * 16 + quad * 4 + r)) * S + n0 + ni * 16 + col;
        OUT[idx] = (om * RES[idx] + tc * acc[mi][ni][r]) * inv;
      }
}

// ---------------- launch ----------------
extern "C" void kernel_launch(void* const* d_in, const int* in_sizes, int n_in,
                              void* d_out, int out_size, void* d_ws, size_t ws_size,
                              hipStream_t stream) {
  const float* x = (const float*)d_in[0];
  const float* w_qkv = (const float*)d_in[1];
  const float* w_out = (const float*)d_in[2];
  float* out = (float*)d_out;

  ushort* p = (ushort*)d_ws;
  ushort* wqb = p; p += (size_t)C3 * CIN;
  ushort* wob = p; p += (size_t)CIN * CIN;
  ushort* Qn = p; p += (size_t)2 * NH * S * HD;
  ushort* Kn = p; p += (size_t)2 * NH * S * HD;
  ushort* Vt = p; p += (size_t)2 * NH * S * HD;
  ushort* Yt = p; p += (size_t)2 * S * CIN;
  // Region R: Xt (4 MB bf16) dies after conv1_fused; accP fp32
  // (KSPLIT*2*8*4096*32 floats = 16.78 MB) aliases the same region.
  ushort* R = p; p += (size_t)KSPLIT * 2 * NH * S * HD * 2;  // 16.78 MB
  ushort* Xt = R;
  float* accP = (float*)R;
  float* lP = (float*)p;  // KSPLIT*2*8*4096 floats = 0.5 MB

  wnorm_kernel<<<(C3 + CIN) / 4, 256, 0, stream>>>(w_qkv, w_out, wqb, wob);
  xt_kernel<<<dim3(S / 64, CIN / 64, 2), 256, 0, stream>>>(x, Xt);
  conv1_fused_kernel<<<dim3(S / 128, C3 / 64, 2), 256, 0, stream>>>(wqb, Xt, Qn, Kn, Vt);
  attn_kernel<<<dim3(S / 128, NH * KSPLIT, 2), 256, 0, stream>>>(Qn, Kn, Vt, accP, lP);
  combine_kernel<<<2048, 256, 0, stream>>>(accP, lP, Yt);
  conv2_kernel<<<dim3(S / 128, CIN / 64, 2), 256, 0, stream>>>(wob, Yt, x, out);
}